// Round 7
// baseline (417.434 us; speedup 1.0000x reference)
//
#include <hip/hip_runtime.h>
#include <hip/hip_bf16.h>

#define TT 16      // in_length
#define EE 32      // embedding size
#define HH 64      // encoder size
#define NGRP 32    // vehicles per group
#define CC 3       // classes

typedef __attribute__((ext_vector_type(8))) short short8;
typedef __attribute__((ext_vector_type(4))) float floatx4;

#define MFMA16(a, b, c) __builtin_amdgcn_mfma_f32_16x16x32_bf16((a), (b), (c), 0, 0, 0)

#define RLN2 1.4426950408889634f   // 1/ln2

__device__ __forceinline__ float leakyf(float x) { return fmaxf(x, 0.1f * x); }
__device__ __forceinline__ short f2bf(float x) {   // fp32 -> bf16 RNE (one-time weights)
    unsigned u = __float_as_uint(x);
    return (short)((u + 0x7FFFu + ((u >> 16) & 1u)) >> 16);
}
__device__ __forceinline__ short f2bf_h(float x) { // fp32 -> bf16 round-half-up (per-step)
    return (short)((__float_as_uint(x) + 0x8000u) >> 16);
}
__device__ __forceinline__ float bf2f(short s) {
    return __uint_as_float(((unsigned)(unsigned short)s) << 16);
}
__device__ __forceinline__ short8 ld8bf(const float* __restrict__ p) {
    const float4 a = *(const float4*)p;
    const float4 b = *(const float4*)(p + 4);
    short8 v;
    v[0] = f2bf(a.x); v[1] = f2bf(a.y); v[2] = f2bf(a.z); v[3] = f2bf(a.w);
    v[4] = f2bf(b.x); v[5] = f2bf(b.y); v[6] = f2bf(b.z); v[7] = f2bf(b.w);
    return v;
}
__device__ __forceinline__ short8 ld8bfs(const float* __restrict__ p, float s) {
    const float4 a = *(const float4*)p;
    const float4 b = *(const float4*)(p + 4);
    short8 v;
    v[0] = f2bf(a.x * s); v[1] = f2bf(a.y * s); v[2] = f2bf(a.z * s); v[3] = f2bf(a.w * s);
    v[4] = f2bf(b.x * s); v[5] = f2bf(b.y * s); v[6] = f2bf(b.z * s); v[7] = f2bf(b.w * s);
    return v;
}

// ---------------------------------------------------------------------------
// ONE fused kernel. Block g = scene group g. 512 threads = 8 waves.
// Phase 1 (GRU): waves 0-3 fwd, 4-7 bwd; wave wd owns gate cols [16wd,16wd+16).
//   Hf DOUBLE-BUFFERED -> ONE barrier per step. Gate biases folded into the
//   MFMA C-operand; B-frags pre-scaled by -1/ln2 (r,z) / 2/ln2 (n) so the
//   nonlinearity uses raw v_exp_f32 (exp2): sigma(x)=rcp(1+exp2(-x/ln2)),
//   tanh(t)=1-2*rcp(exp2(2t/ln2)+1).
//   Hf slot index permuted (slot = qa*16 + r*4 + quad) -> h-write bank
//   conflicts 4-way -> 2-way (free); readers use permuted lane rlane.
// Phase 2 (spatial MFMA) + Phase 3 (head): unchanged from R6 (proven);
//   spatial arrays overlay dead Xall in a union, Hf preserved for epilogue.
//   A-frag: A[m=lane&15][k] at slot=((k>>3)&3)*16+m (permuted), elem k&7
//   B-frag: B[k=(lane>>4)*8+i][n=lane&15]
//   C/D   : row=(lane>>4)*4+reg, col=lane&15
// ---------------------------------------------------------------------------
__global__ __launch_bounds__(512, 6) void fused_kernel(
    const float* __restrict__ scene, const int* __restrict__ index_div,
    const float* __restrict__ W_emb, const float* __restrict__ b_emb,
    const float* __restrict__ Wih_f, const float* __restrict__ Whh_f,
    const float* __restrict__ bih_f, const float* __restrict__ bhh_f,
    const float* __restrict__ Wih_b, const float* __restrict__ Whh_b,
    const float* __restrict__ bih_b, const float* __restrict__ bhh_b,
    const float* __restrict__ Wm, const float* __restrict__ bm,
    const float* __restrict__ Ws1, const float* __restrict__ bs1,
    const float* __restrict__ Ws2, const float* __restrict__ bs2,
    const float* __restrict__ Wo1, const float* __restrict__ bo1,
    const float* __restrict__ Wo2, const float* __restrict__ bo2,
    float* __restrict__ full_enc, float* __restrict__ out)
{
    __shared__ float sscene[32][33];                 // [c][veh], 4.2 KB, persists
    __shared__ __align__(16) union SmemU {
        struct {                                     // GRU phase
            short Xall[16 * 2 * 64 * 8];             // [t][mt][lane][8]   32 KB
            short Hf[2 * 2 * 2 * 2 * 64 * 8];        // [dir][buf][ks][mt][slot][8] 16 KB
        } g;
        struct {                                     // spatial/head phase (21.6 KB < 32 KB)
            float su[NGRP][68];
            float fe[NGRP][68];
            float swo1[1024];
            float szero[32];
        } s;
    } sm;

    const int g    = blockIdx.x;
    const int tid  = threadIdx.x;
    const int lane = tid & 63;
    const int w    = __builtin_amdgcn_readfirstlane(tid >> 6);  // 0..7
    const int dir  = w >> 2;
    const int wd   = w & 3;
    const int cc   = lane & 15;
    const int quad = lane >> 4;
    const int j    = wd * 16 + cc;            // gate column
    const int ks_w = j >> 5;
    const int qa_w = (j >> 3) & 3;
    const int ii_w = j & 7;
    // permuted reader lane: slot(Lq, m) = Lq*16 + (m&3)*4 + (m>>2)
    const int rlane = (lane & 48) | ((lane & 3) << 2) | ((lane >> 2) & 3);

    // ---- stage gathered scene rows into sscene[c][veh] ----
    #pragma unroll
    for (int rep = 0; rep < 2; ++rep) {
        const int idx = tid + rep * 512;
        const int v = idx >> 5, c = idx & 31;
        const int n = index_div[g * NGRP + v];
        sscene[c][v] = scene[n * 32 + c];
    }

    // ---- per-wave GRU B-frags, pre-scaled; biases as MFMA C-init ----
    const float* Wih = dir ? Wih_b : Wih_f;
    const float* Whh = dir ? Whh_b : Whh_f;
    const float* bih = dir ? bih_b : bih_f;
    const float* bhh = dir ? bhh_b : bhh_f;
    const int k0 = quad * 8;
    const float SRZ = -RLN2, SN = 2.0f * RLN2;
    const short8 Br0  = ld8bfs(Whh + (j      ) * 64 + k0,      SRZ);
    const short8 Br1  = ld8bfs(Whh + (j      ) * 64 + 32 + k0, SRZ);
    const short8 Br2  = ld8bfs(Wih + (j      ) * 32 + k0,      SRZ);
    const short8 Bz0  = ld8bfs(Whh + (j +  64) * 64 + k0,      SRZ);
    const short8 Bz1  = ld8bfs(Whh + (j +  64) * 64 + 32 + k0, SRZ);
    const short8 Bz2  = ld8bfs(Wih + (j +  64) * 32 + k0,      SRZ);
    const short8 Bhn0 = ld8bfs(Whh + (j + 128) * 64 + k0,      SN);
    const short8 Bhn1 = ld8bfs(Whh + (j + 128) * 64 + 32 + k0, SN);
    const short8 Bxn  = ld8bfs(Wih + (j + 128) * 32 + k0,      SN);
    const float vb_r  = SRZ * (bih[j] + bhh[j]);
    const float vb_z  = SRZ * (bih[j + 64] + bhh[j + 64]);
    const float vb_xn = SN * bih[j + 128];
    const float vb_hn = SN * bhh[j + 128];
    const floatx4 c_r  = {vb_r,  vb_r,  vb_r,  vb_r };
    const floatx4 c_z  = {vb_z,  vb_z,  vb_z,  vb_z };
    const floatx4 c_xn = {vb_xn, vb_xn, vb_xn, vb_xn};
    const floatx4 c_hn = {vb_hn, vb_hn, vb_hn, vb_hn};

    __syncthreads();   // sscene ready

    // ---- emb for ALL t (512 threads = 16 t x 32 veh); zero Hf buf0 ----
    {
        const int t   = tid >> 5;
        const int veh = tid & 31;
        const float xs = sscene[t][veh];
        const float ys = sscene[16 + t][veh];
        const int mt = veh >> 4;
        const int m  = veh & 15;
        #pragma unroll
        for (int q = 0; q < 4; ++q) {
            short8 v;
            #pragma unroll
            for (int i2 = 0; i2 < 8; ++i2) {
                const int e = q * 8 + i2;
                v[i2] = f2bf(leakyf(fmaf(xs, W_emb[e], fmaf(ys, W_emb[EE + e], b_emb[e]))));
            }
            *(short8*)&sm.g.Xall[(((t * 2 + mt) * 64) + q * 16 + m) * 8] = v;
        }
        // zero buf0 of both dirs: dir block = 4096 shorts, buf0 = first 2048
        const short8 z8 = {0, 0, 0, 0, 0, 0, 0, 0};
        *(short8*)&sm.g.Hf[(tid >> 8) * 4096 + (tid & 255) * 8] = z8;
    }

    float h_reg[8];
    #pragma unroll
    for (int i = 0; i < 8; ++i) h_reg[i] = 0.0f;

    const int hf_dir = dir * 4096;                 // shorts
    __syncthreads();

    // ---- GRU main loop: ONE barrier per step (Hf double-buffered) ----
    #pragma unroll 2
    for (int s = 0; s < TT; ++s) {
        const int pb = s & 1, nb = pb ^ 1;
        const int t  = dir ? (TT - 1 - s) : s;
        const short* HfD = &sm.g.Hf[hf_dir + pb * 2048];
        short*       HfN = &sm.g.Hf[hf_dir + nb * 2048];
        #pragma unroll
        for (int mt = 0; mt < 2; ++mt) {
            const short8 Ah0 = *(const short8*)&HfD[((0 * 2 + mt) * 64 + rlane) * 8];
            const short8 Ah1 = *(const short8*)&HfD[((1 * 2 + mt) * 64 + rlane) * 8];
            const short8 Axx = *(const short8*)&sm.g.Xall[((t * 2 + mt) * 64 + lane) * 8];
            const floatx4 ar  = MFMA16(Axx, Br2, MFMA16(Ah1, Br1, MFMA16(Ah0, Br0, c_r)));
            const floatx4 az  = MFMA16(Axx, Bz2, MFMA16(Ah1, Bz1, MFMA16(Ah0, Bz0, c_z)));
            const floatx4 ahn = MFMA16(Ah1, Bhn1, MFMA16(Ah0, Bhn0, c_hn));
            const floatx4 axn = MFMA16(Axx, Bxn, c_xn);
            #pragma unroll
            for (int r = 0; r < 4; ++r) {
                // rr = sigmoid(pre_r): ar = -pre_r/ln2
                const float rr = __builtin_amdgcn_rcpf(1.0f + __builtin_amdgcn_exp2f(ar[r]));
                const float zz = __builtin_amdgcn_rcpf(1.0f + __builtin_amdgcn_exp2f(az[r]));
                // ng = tanh(xn + rr*hn): y = 2*(xn + rr*hn)/ln2
                const float y  = fmaf(rr, ahn[r], axn[r]);
                const float ng = fmaf(-2.0f,
                                      __builtin_amdgcn_rcpf(__builtin_amdgcn_exp2f(y) + 1.0f),
                                      1.0f);
                const float h0 = h_reg[mt * 4 + r];
                h_reg[mt * 4 + r] = fmaf(zz, h0 - ng, ng);  // (1-z)*ng + z*h
            }
        }
        // write new h into buf nb with permuted slot (2-way banks)
        #pragma unroll
        for (int mt = 0; mt < 2; ++mt) {
            #pragma unroll
            for (int r = 0; r < 4; ++r) {
                const int slot = qa_w * 16 + r * 4 + quad;   // perm of qa*16 + m
                HfN[((ks_w * 2 + mt) * 64 + slot) * 8 + ii_w] = f2bf_h(h_reg[mt * 4 + r]);
            }
        }
        __syncthreads();
    }
    // Final h in Hf[dir][buf0]. Xall dead from here.

    // ---- Phase 2 prep: waves 0-3 seq_enc epilogue; waves 4-7 su/swo1/szero ----
    if (w < 4) {
        const int nt   = w >> 1;
        const int mt_e = w & 1;
        const int n_col = nt * 16 + cc;
        short8 Bm0, Bm1;
        #pragma unroll
        for (int i = 0; i < 8; ++i) {
            Bm0[i] = f2bf(Wm[(     quad * 8 + i) * 32 + n_col]);
            Bm1[i] = f2bf(Wm[(32 + quad * 8 + i) * 32 + n_col]);
        }
        short8 A0, A1;
        #pragma unroll
        for (int ks = 0; ks < 2; ++ks) {
            const short8 F = *(const short8*)&sm.g.Hf[0    + ((ks * 2 + mt_e) * 64 + rlane) * 8];
            const short8 B = *(const short8*)&sm.g.Hf[4096 + ((ks * 2 + mt_e) * 64 + rlane) * 8];
            #pragma unroll
            for (int i = 0; i < 8; ++i) {
                const short v = f2bf(0.5f * (bf2f(F[i]) + bf2f(B[i])));
                if (ks == 0) A0[i] = v; else A1[i] = v;
            }
        }
        const floatx4 z4 = {0.f, 0.f, 0.f, 0.f};
        const floatx4 acc = MFMA16(A1, Bm1, MFMA16(A0, Bm0, z4));
        const float bmn = bm[n_col];
        #pragma unroll
        for (int r = 0; r < 4; ++r) {
            const int veh = mt_e * 16 + quad * 4 + r;
            const float sv = leakyf(acc[r] + bmn);
            const int n = index_div[g * NGRP + veh];
            full_enc[n * HH + n_col] = sv;
            sm.s.fe[veh][n_col] = sv;     // fe region does not overlap Hf
        }
    } else {
        const int l  = tid & 255;
        const int v  = l >> 3;
        const int d0 = (l & 7) * 8;
        float acc[8];
        #pragma unroll
        for (int i = 0; i < 8; ++i) acc[i] = 0.0f;
        #pragma unroll
        for (int e = 0; e < EE; ++e) {
            const float f = sscene[e][v];
            const float4 w0 = *(const float4*)&Ws1[e * 64 + d0];
            const float4 w1 = *(const float4*)&Ws1[e * 64 + d0 + 4];
            acc[0] = fmaf(f, w0.x, acc[0]); acc[1] = fmaf(f, w0.y, acc[1]);
            acc[2] = fmaf(f, w0.z, acc[2]); acc[3] = fmaf(f, w0.w, acc[3]);
            acc[4] = fmaf(f, w1.x, acc[4]); acc[5] = fmaf(f, w1.y, acc[5]);
            acc[6] = fmaf(f, w1.z, acc[6]); acc[7] = fmaf(f, w1.w, acc[7]);
        }
        #pragma unroll
        for (int i = 0; i < 8; ++i) sm.s.su[v][d0 + i] = acc[i];
        *(float4*)&sm.s.swo1[l * 4] = *(const float4*)&Wo1[l * 4];
        if (l < 32) {
            float zs = bs2[l];
            #pragma unroll
            for (int d = 0; d < HH; ++d) zs = fmaf(leakyf(bs1[d]), Ws2[d * 32 + l], zs);
            sm.s.szero[l] = leakyf(zs);
        }
    }

    // ---- spatial B-frags (all 8 waves) ----
    short8 Bw00, Bw01, Bw10, Bw11;
    #pragma unroll
    for (int i = 0; i < 8; ++i) {
        Bw00[i] = f2bf(Ws2[(     quad * 8 + i) * 32 + cc]);
        Bw01[i] = f2bf(Ws2[(32 + quad * 8 + i) * 32 + cc]);
        Bw10[i] = f2bf(Ws2[(     quad * 8 + i) * 32 + 16 + cc]);
        Bw11[i] = f2bf(Ws2[(32 + quad * 8 + i) * 32 + 16 + cc]);
    }
    float bsq0[8], bsq1[8];
    #pragma unroll
    for (int i = 0; i < 8; ++i) {
        bsq0[i] = bs1[quad * 8 + i];
        bsq1[i] = bs1[32 + quad * 8 + i];
    }
    const float bs2c0 = bs2[cc], bs2c1 = bs2[16 + cc];
    __syncthreads();

    // ---- spatial pairwise MLP: 8 waves x 4 j's ----
    #pragma unroll 2
    for (int jj = 0; jj < 4; ++jj) {
        const int jrow = w * 4 + jj;       // wave-uniform j, 0..31
        float vj0[8], vj1[8];
        #pragma unroll
        for (int i = 0; i < 8; ++i) {
            vj0[i] = sm.s.su[jrow][quad * 8 + i] - bsq0[i];
            vj1[i] = sm.s.su[jrow][32 + quad * 8 + i] - bsq1[i];
        }
        float acc0 = 0.0f, acc1 = 0.0f;
        #pragma unroll
        for (int it = 0; it < 2; ++it) {
            const int irow = it * 16 + cc;   // A-frag row m = cc
            const float4 p0 = *(const float4*)&sm.s.su[irow][quad * 8];
            const float4 p1 = *(const float4*)&sm.s.su[irow][quad * 8 + 4];
            const float4 p2 = *(const float4*)&sm.s.su[irow][32 + quad * 8];
            const float4 p3 = *(const float4*)&sm.s.su[irow][32 + quad * 8 + 4];
            short8 A0, A1;
            A0[0] = f2bf(leakyf(p0.x - vj0[0])); A0[1] = f2bf(leakyf(p0.y - vj0[1]));
            A0[2] = f2bf(leakyf(p0.z - vj0[2])); A0[3] = f2bf(leakyf(p0.w - vj0[3]));
            A0[4] = f2bf(leakyf(p1.x - vj0[4])); A0[5] = f2bf(leakyf(p1.y - vj0[5]));
            A0[6] = f2bf(leakyf(p1.z - vj0[6])); A0[7] = f2bf(leakyf(p1.w - vj0[7]));
            A1[0] = f2bf(leakyf(p2.x - vj1[0])); A1[1] = f2bf(leakyf(p2.y - vj1[1]));
            A1[2] = f2bf(leakyf(p2.z - vj1[2])); A1[3] = f2bf(leakyf(p2.w - vj1[3]));
            A1[4] = f2bf(leakyf(p3.x - vj1[4])); A1[5] = f2bf(leakyf(p3.y - vj1[5]));
            A1[6] = f2bf(leakyf(p3.z - vj1[6])); A1[7] = f2bf(leakyf(p3.w - vj1[7]));
            const floatx4 z4 = {0.f, 0.f, 0.f, 0.f};
            const floatx4 D0 = MFMA16(A1, Bw01, MFMA16(A0, Bw00, z4));
            const floatx4 D1 = MFMA16(A1, Bw11, MFMA16(A0, Bw10, z4));
            #pragma unroll
            for (int r = 0; r < 4; ++r) {
                acc0 += leakyf(D0[r] + bs2c0);
                acc1 += leakyf(D1[r] + bs2c1);
            }
        }
        acc0 += __shfl_xor(acc0, 16, 64); acc0 += __shfl_xor(acc0, 32, 64);
        acc1 += __shfl_xor(acc1, 16, 64); acc1 += __shfl_xor(acc1, 32, 64);
        const int n = index_div[g * NGRP + jrow];
        if (quad == 0) {
            const float pv = (acc0 - sm.s.szero[cc]) * (1.0f / 31.0f);
            full_enc[n * HH + 32 + cc] = pv;
            sm.s.fe[jrow][32 + cc] = pv;
        } else if (quad == 1) {
            const float pv = (acc1 - sm.s.szero[16 + cc]) * (1.0f / 31.0f);
            full_enc[n * HH + 48 + cc] = pv;
            sm.s.fe[jrow][48 + cc] = pv;
        }
    }
    __syncthreads();

    // ---- head: x_logit = leaky(fe @ Wo1 + bo1) @ Wo2 + bo2 ----
    {
        const int veh = tid >> 4;          // 0..31
        const int p   = tid & 15;          // hidden dim
        float a = bo1[p];
        #pragma unroll
        for (int k = 0; k < HH; ++k)
            a = fmaf(sm.s.fe[veh][k], sm.s.swo1[k * 16 + p], a);
        a = leakyf(a);
        float l0 = a * Wo2[p * 3 + 0];
        float l1 = a * Wo2[p * 3 + 1];
        float l2 = a * Wo2[p * 3 + 2];
        #pragma unroll
        for (int off = 1; off < 16; off <<= 1) {
            l0 += __shfl_xor(l0, off, 64);
            l1 += __shfl_xor(l1, off, 64);
            l2 += __shfl_xor(l2, off, 64);
        }
        if (p == 0) {
            const int n = index_div[g * NGRP + veh];
            out[n * 3 + 0] = l0 + bo2[0];
            out[n * 3 + 1] = l1 + bo2[1];
            out[n * 3 + 2] = l2 + bo2[2];
        }
    }
}

// ---------------------------------------------------------------------------
extern "C" void kernel_launch(void* const* d_in, const int* in_sizes, int n_in,
                              void* d_out, int out_size, void* d_ws, size_t ws_size,
                              hipStream_t stream) {
    const float* scene     = (const float*)d_in[0];
    const int*   index_div = (const int*)d_in[4];
    const float* W_emb = (const float*)d_in[5];
    const float* b_emb = (const float*)d_in[6];
    const float* Wih_f = (const float*)d_in[7];
    const float* Whh_f = (const float*)d_in[8];
    const float* bih_f = (const float*)d_in[9];
    const float* bhh_f = (const float*)d_in[10];
    const float* Wih_b = (const float*)d_in[11];
    const float* Whh_b = (const float*)d_in[12];
    const float* bih_b = (const float*)d_in[13];
    const float* bhh_b = (const float*)d_in[14];
    const float* Wm  = (const float*)d_in[15];
    const float* bm  = (const float*)d_in[16];
    const float* Ws1 = (const float*)d_in[17];
    const float* bs1 = (const float*)d_in[18];
    const float* Ws2 = (const float*)d_in[19];
    const float* bs2 = (const float*)d_in[20];
    const float* Wo1 = (const float*)d_in[21];
    const float* bo1 = (const float*)d_in[22];
    const float* Wo2 = (const float*)d_in[23];
    const float* bo2 = (const float*)d_in[24];

    const int N = in_sizes[0] / (2 * TT);   // 32768
    const int G = in_sizes[4] / NGRP;       // 1024

    float* out      = (float*)d_out;
    float* full_enc = out + (size_t)N * CC;

    fused_kernel<<<dim3(G), dim3(512), 0, stream>>>(
        scene, index_div, W_emb, b_emb, Wih_f, Whh_f, bih_f, bhh_f,
        Wih_b, Whh_b, bih_b, bhh_b, Wm, bm, Ws1, bs1, Ws2, bs2,
        Wo1, bo1, Wo2, bo2, full_enc, out);
}

// Round 8
// 192.971 us; speedup vs baseline: 2.1632x; 2.1632x over previous
//
#include <hip/hip_runtime.h>
#include <hip/hip_bf16.h>

#define TT 16      // in_length
#define EE 32      // embedding size
#define HH 64      // encoder size
#define NGRP 32    // vehicles per group
#define CC 3       // classes

typedef __attribute__((ext_vector_type(8))) short short8;
typedef __attribute__((ext_vector_type(4))) float floatx4;

#define MFMA16(a, b, c) __builtin_amdgcn_mfma_f32_16x16x32_bf16((a), (b), (c), 0, 0, 0)

#define RLN2 1.4426950408889634f   // 1/ln2

__device__ __forceinline__ float leakyf(float x) { return fmaxf(x, 0.1f * x); }
__device__ __forceinline__ short f2bf(float x) {   // fp32 -> bf16 RNE (one-time weights)
    unsigned u = __float_as_uint(x);
    return (short)((u + 0x7FFFu + ((u >> 16) & 1u)) >> 16);
}
__device__ __forceinline__ short f2bf_h(float x) { // fp32 -> bf16 round-half-up (per-step)
    return (short)((__float_as_uint(x) + 0x8000u) >> 16);
}
__device__ __forceinline__ float bf2f(short s) {
    return __uint_as_float(((unsigned)(unsigned short)s) << 16);
}
__device__ __forceinline__ short8 ld8bf(const float* __restrict__ p) {
    const float4 a = *(const float4*)p;
    const float4 b = *(const float4*)(p + 4);
    short8 v;
    v[0] = f2bf(a.x); v[1] = f2bf(a.y); v[2] = f2bf(a.z); v[3] = f2bf(a.w);
    v[4] = f2bf(b.x); v[5] = f2bf(b.y); v[6] = f2bf(b.z); v[7] = f2bf(b.w);
    return v;
}
__device__ __forceinline__ short8 ld8bfs(const float* __restrict__ p, float s) {
    const float4 a = *(const float4*)p;
    const float4 b = *(const float4*)(p + 4);
    short8 v;
    v[0] = f2bf(a.x * s); v[1] = f2bf(a.y * s); v[2] = f2bf(a.z * s); v[3] = f2bf(a.w * s);
    v[4] = f2bf(b.x * s); v[5] = f2bf(b.y * s); v[6] = f2bf(b.z * s); v[7] = f2bf(b.w * s);
    return v;
}

// ---------------------------------------------------------------------------
// ONE fused kernel. Block g = scene group g. 512 threads = 8 waves.
// Phase 1 (GRU): waves 0-3 fwd, 4-7 bwd; wave wd owns gate cols [16wd,16wd+16).
//   Hf double-buffered -> ONE barrier/step (R5/R7-validated). B-frags
//   pre-scaled by -1/ln2 (r,z) / 2/ln2 (n); biases added as SCALARS after the
//   MFMA (NOT floatx4 C-inits: R5/R7 showed those spill the B-frags — the
//   16 extra loop-live VGPRs blow the allocator budget). Gates use raw
//   exp2+rcp: sigma(x)=rcp(1+exp2(-x/ln2)), tanh(t)=1-2*rcp(exp2(2t/ln2)+1).
//   Hf write slot permuted (slot = qa*16 + r*4 + quad): 8-way -> 4-way write
//   bank conflicts; reads use permuted lane rlane (bank multiset unchanged).
// Phase 2 (spatial MFMA) + Phase 3 (head): proven R6 structure; spatial
//   arrays overlay dead Xall in a union; Hf region preserved for epilogue.
//   launch_bounds(512,4): 128-VGPR cap — R6-proven no-spill shape.
// ---------------------------------------------------------------------------
__global__ __launch_bounds__(512, 4) void fused_kernel(
    const float* __restrict__ scene, const int* __restrict__ index_div,
    const float* __restrict__ W_emb, const float* __restrict__ b_emb,
    const float* __restrict__ Wih_f, const float* __restrict__ Whh_f,
    const float* __restrict__ bih_f, const float* __restrict__ bhh_f,
    const float* __restrict__ Wih_b, const float* __restrict__ Whh_b,
    const float* __restrict__ bih_b, const float* __restrict__ bhh_b,
    const float* __restrict__ Wm, const float* __restrict__ bm,
    const float* __restrict__ Ws1, const float* __restrict__ bs1,
    const float* __restrict__ Ws2, const float* __restrict__ bs2,
    const float* __restrict__ Wo1, const float* __restrict__ bo1,
    const float* __restrict__ Wo2, const float* __restrict__ bo2,
    float* __restrict__ full_enc, float* __restrict__ out)
{
    __shared__ float sscene[32][33];                 // [c][veh], 4.2 KB, persists
    __shared__ __align__(16) union SmemU {
        struct {                                     // GRU phase
            short Xall[16 * 2 * 64 * 8];             // [t][mt][lane][8]   32 KB
            short Hf[2 * 2 * 2 * 2 * 64 * 8];        // [dir][buf][ks][mt][slot][8] 16 KB
        } g;
        struct {                                     // spatial/head phase (21.6 KB < 32 KB)
            float su[NGRP][68];
            float fe[NGRP][68];
            float swo1[1024];
            float szero[32];
        } s;
    } sm;

    const int g    = blockIdx.x;
    const int tid  = threadIdx.x;
    const int lane = tid & 63;
    const int w    = __builtin_amdgcn_readfirstlane(tid >> 6);  // 0..7
    const int dir  = w >> 2;
    const int wd   = w & 3;
    const int cc   = lane & 15;
    const int quad = lane >> 4;
    const int j    = wd * 16 + cc;            // gate column
    const int ks_w = j >> 5;
    const int qa_w = (j >> 3) & 3;
    const int ii_w = j & 7;
    // permuted reader lane: slot(Lq, m) = Lq*16 + (m&3)*4 + (m>>2)
    const int rlane = (lane & 48) | ((lane & 3) << 2) | ((lane >> 2) & 3);

    // ---- stage gathered scene rows into sscene[c][veh] ----
    #pragma unroll
    for (int rep = 0; rep < 2; ++rep) {
        const int idx = tid + rep * 512;
        const int v = idx >> 5, c = idx & 31;
        const int n = index_div[g * NGRP + v];
        sscene[c][v] = scene[n * 32 + c];
    }

    // ---- per-wave GRU B-frags, pre-scaled; biases stay SCALAR ----
    const float* Wih = dir ? Wih_b : Wih_f;
    const float* Whh = dir ? Whh_b : Whh_f;
    const float* bih = dir ? bih_b : bih_f;
    const float* bhh = dir ? bhh_b : bhh_f;
    const int k0 = quad * 8;
    const float SRZ = -RLN2, SN = 2.0f * RLN2;
    const short8 Br0  = ld8bfs(Whh + (j      ) * 64 + k0,      SRZ);
    const short8 Br1  = ld8bfs(Whh + (j      ) * 64 + 32 + k0, SRZ);
    const short8 Br2  = ld8bfs(Wih + (j      ) * 32 + k0,      SRZ);
    const short8 Bz0  = ld8bfs(Whh + (j +  64) * 64 + k0,      SRZ);
    const short8 Bz1  = ld8bfs(Whh + (j +  64) * 64 + 32 + k0, SRZ);
    const short8 Bz2  = ld8bfs(Wih + (j +  64) * 32 + k0,      SRZ);
    const short8 Bhn0 = ld8bfs(Whh + (j + 128) * 64 + k0,      SN);
    const short8 Bhn1 = ld8bfs(Whh + (j + 128) * 64 + 32 + k0, SN);
    const short8 Bxn  = ld8bfs(Wih + (j + 128) * 32 + k0,      SN);
    const float vb_r  = SRZ * (bih[j] + bhh[j]);
    const float vb_z  = SRZ * (bih[j + 64] + bhh[j + 64]);
    const float vb_xn = SN * bih[j + 128];
    const float vb_hn = SN * bhh[j + 128];

    __syncthreads();   // sscene ready

    // ---- emb for ALL t (512 threads = 16 t x 32 veh); zero Hf buf0 ----
    {
        const int t   = tid >> 5;
        const int veh = tid & 31;
        const float xs = sscene[t][veh];
        const float ys = sscene[16 + t][veh];
        const int mt = veh >> 4;
        const int m  = veh & 15;
        #pragma unroll
        for (int q = 0; q < 4; ++q) {
            short8 v;
            #pragma unroll
            for (int i2 = 0; i2 < 8; ++i2) {
                const int e = q * 8 + i2;
                v[i2] = f2bf(leakyf(fmaf(xs, W_emb[e], fmaf(ys, W_emb[EE + e], b_emb[e]))));
            }
            *(short8*)&sm.g.Xall[(((t * 2 + mt) * 64) + q * 16 + m) * 8] = v;
        }
        // zero buf0 of both dirs: dir block = 4096 shorts, buf0 = first 2048
        const short8 z8 = {0, 0, 0, 0, 0, 0, 0, 0};
        *(short8*)&sm.g.Hf[(tid >> 8) * 4096 + (tid & 255) * 8] = z8;
    }

    float h_reg[8];
    #pragma unroll
    for (int i = 0; i < 8; ++i) h_reg[i] = 0.0f;

    const int hf_dir = dir * 4096;                 // shorts
    __syncthreads();

    // ---- GRU main loop: ONE barrier per step (Hf double-buffered) ----
    #pragma unroll 2
    for (int s = 0; s < TT; ++s) {
        const int pb = s & 1, nb = pb ^ 1;
        const int t  = dir ? (TT - 1 - s) : s;
        const short* HfD = &sm.g.Hf[hf_dir + pb * 2048];
        short*       HfN = &sm.g.Hf[hf_dir + nb * 2048];
        #pragma unroll
        for (int mt = 0; mt < 2; ++mt) {
            const short8 Ah0 = *(const short8*)&HfD[((0 * 2 + mt) * 64 + rlane) * 8];
            const short8 Ah1 = *(const short8*)&HfD[((1 * 2 + mt) * 64 + rlane) * 8];
            const short8 Axx = *(const short8*)&sm.g.Xall[((t * 2 + mt) * 64 + lane) * 8];
            const floatx4 z4 = {0.f, 0.f, 0.f, 0.f};
            const floatx4 ar  = MFMA16(Axx, Br2, MFMA16(Ah1, Br1, MFMA16(Ah0, Br0, z4)));
            const floatx4 az  = MFMA16(Axx, Bz2, MFMA16(Ah1, Bz1, MFMA16(Ah0, Bz0, z4)));
            const floatx4 ahn = MFMA16(Ah1, Bhn1, MFMA16(Ah0, Bhn0, z4));
            const floatx4 axn = MFMA16(Axx, Bxn, z4);
            #pragma unroll
            for (int r = 0; r < 4; ++r) {
                // ar = -pre_r/ln2 (pre-scaled); rr = sigmoid(pre_r)
                const float rr = __builtin_amdgcn_rcpf(1.0f + __builtin_amdgcn_exp2f(ar[r] + vb_r));
                const float zz = __builtin_amdgcn_rcpf(1.0f + __builtin_amdgcn_exp2f(az[r] + vb_z));
                // y = 2*(xn + rr*hn)/ln2 ; ng = tanh(xn + rr*hn)
                const float y  = fmaf(rr, ahn[r] + vb_hn, axn[r] + vb_xn);
                const float ng = fmaf(-2.0f,
                                      __builtin_amdgcn_rcpf(__builtin_amdgcn_exp2f(y) + 1.0f),
                                      1.0f);
                const float h0 = h_reg[mt * 4 + r];
                h_reg[mt * 4 + r] = fmaf(zz, h0 - ng, ng);  // (1-z)*ng + z*h
            }
        }
        // write new h into buf nb with permuted slot (4-way banks, was 8-way)
        #pragma unroll
        for (int mt = 0; mt < 2; ++mt) {
            #pragma unroll
            for (int r = 0; r < 4; ++r) {
                const int slot = qa_w * 16 + r * 4 + quad;   // perm of qa*16 + m
                HfN[((ks_w * 2 + mt) * 64 + slot) * 8 + ii_w] = f2bf_h(h_reg[mt * 4 + r]);
            }
        }
        __syncthreads();
    }
    // Final h in Hf[dir][buf0]. Xall dead from here.

    // ---- Phase 2 prep: waves 0-3 seq_enc epilogue; waves 4-7 su/swo1/szero ----
    if (w < 4) {
        const int nt   = w >> 1;
        const int mt_e = w & 1;
        const int n_col = nt * 16 + cc;
        short8 Bm0, Bm1;
        #pragma unroll
        for (int i = 0; i < 8; ++i) {
            Bm0[i] = f2bf(Wm[(     quad * 8 + i) * 32 + n_col]);
            Bm1[i] = f2bf(Wm[(32 + quad * 8 + i) * 32 + n_col]);
        }
        short8 A0, A1;
        #pragma unroll
        for (int ks = 0; ks < 2; ++ks) {
            const short8 F = *(const short8*)&sm.g.Hf[0    + ((ks * 2 + mt_e) * 64 + rlane) * 8];
            const short8 B = *(const short8*)&sm.g.Hf[4096 + ((ks * 2 + mt_e) * 64 + rlane) * 8];
            #pragma unroll
            for (int i = 0; i < 8; ++i) {
                const short v = f2bf(0.5f * (bf2f(F[i]) + bf2f(B[i])));
                if (ks == 0) A0[i] = v; else A1[i] = v;
            }
        }
        const floatx4 z4 = {0.f, 0.f, 0.f, 0.f};
        const floatx4 acc = MFMA16(A1, Bm1, MFMA16(A0, Bm0, z4));
        const float bmn = bm[n_col];
        #pragma unroll
        for (int r = 0; r < 4; ++r) {
            const int veh = mt_e * 16 + quad * 4 + r;
            const float sv = leakyf(acc[r] + bmn);
            const int n = index_div[g * NGRP + veh];
            full_enc[n * HH + n_col] = sv;
            sm.s.fe[veh][n_col] = sv;     // fe region does not overlap Hf
        }
    } else {
        const int l  = tid & 255;
        const int v  = l >> 3;
        const int d0 = (l & 7) * 8;
        float acc[8];
        #pragma unroll
        for (int i = 0; i < 8; ++i) acc[i] = 0.0f;
        #pragma unroll
        for (int e = 0; e < EE; ++e) {
            const float f = sscene[e][v];
            const float4 w0 = *(const float4*)&Ws1[e * 64 + d0];
            const float4 w1 = *(const float4*)&Ws1[e * 64 + d0 + 4];
            acc[0] = fmaf(f, w0.x, acc[0]); acc[1] = fmaf(f, w0.y, acc[1]);
            acc[2] = fmaf(f, w0.z, acc[2]); acc[3] = fmaf(f, w0.w, acc[3]);
            acc[4] = fmaf(f, w1.x, acc[4]); acc[5] = fmaf(f, w1.y, acc[5]);
            acc[6] = fmaf(f, w1.z, acc[6]); acc[7] = fmaf(f, w1.w, acc[7]);
        }
        #pragma unroll
        for (int i = 0; i < 8; ++i) sm.s.su[v][d0 + i] = acc[i];
        *(float4*)&sm.s.swo1[l * 4] = *(const float4*)&Wo1[l * 4];
        if (l < 32) {
            float zs = bs2[l];
            #pragma unroll
            for (int d = 0; d < HH; ++d) zs = fmaf(leakyf(bs1[d]), Ws2[d * 32 + l], zs);
            sm.s.szero[l] = leakyf(zs);
        }
    }

    // ---- spatial B-frags (all 8 waves) ----
    short8 Bw00, Bw01, Bw10, Bw11;
    #pragma unroll
    for (int i = 0; i < 8; ++i) {
        Bw00[i] = f2bf(Ws2[(     quad * 8 + i) * 32 + cc]);
        Bw01[i] = f2bf(Ws2[(32 + quad * 8 + i) * 32 + cc]);
        Bw10[i] = f2bf(Ws2[(     quad * 8 + i) * 32 + 16 + cc]);
        Bw11[i] = f2bf(Ws2[(32 + quad * 8 + i) * 32 + 16 + cc]);
    }
    float bsq0[8], bsq1[8];
    #pragma unroll
    for (int i = 0; i < 8; ++i) {
        bsq0[i] = bs1[quad * 8 + i];
        bsq1[i] = bs1[32 + quad * 8 + i];
    }
    const float bs2c0 = bs2[cc], bs2c1 = bs2[16 + cc];
    __syncthreads();

    // ---- spatial pairwise MLP: 8 waves x 4 j's ----
    #pragma unroll 2
    for (int jj = 0; jj < 4; ++jj) {
        const int jrow = w * 4 + jj;       // wave-uniform j, 0..31
        float vj0[8], vj1[8];
        #pragma unroll
        for (int i = 0; i < 8; ++i) {
            vj0[i] = sm.s.su[jrow][quad * 8 + i] - bsq0[i];
            vj1[i] = sm.s.su[jrow][32 + quad * 8 + i] - bsq1[i];
        }
        float acc0 = 0.0f, acc1 = 0.0f;
        #pragma unroll
        for (int it = 0; it < 2; ++it) {
            const int irow = it * 16 + cc;   // A-frag row m = cc
            const float4 p0 = *(const float4*)&sm.s.su[irow][quad * 8];
            const float4 p1 = *(const float4*)&sm.s.su[irow][quad * 8 + 4];
            const float4 p2 = *(const float4*)&sm.s.su[irow][32 + quad * 8];
            const float4 p3 = *(const float4*)&sm.s.su[irow][32 + quad * 8 + 4];
            short8 A0, A1;
            A0[0] = f2bf(leakyf(p0.x - vj0[0])); A0[1] = f2bf(leakyf(p0.y - vj0[1]));
            A0[2] = f2bf(leakyf(p0.z - vj0[2])); A0[3] = f2bf(leakyf(p0.w - vj0[3]));
            A0[4] = f2bf(leakyf(p1.x - vj0[4])); A0[5] = f2bf(leakyf(p1.y - vj0[5]));
            A0[6] = f2bf(leakyf(p1.z - vj0[6])); A0[7] = f2bf(leakyf(p1.w - vj0[7]));
            A1[0] = f2bf(leakyf(p2.x - vj1[0])); A1[1] = f2bf(leakyf(p2.y - vj1[1]));
            A1[2] = f2bf(leakyf(p2.z - vj1[2])); A1[3] = f2bf(leakyf(p2.w - vj1[3]));
            A1[4] = f2bf(leakyf(p3.x - vj1[4])); A1[5] = f2bf(leakyf(p3.y - vj1[5]));
            A1[6] = f2bf(leakyf(p3.z - vj1[6])); A1[7] = f2bf(leakyf(p3.w - vj1[7]));
            const floatx4 z4 = {0.f, 0.f, 0.f, 0.f};
            const floatx4 D0 = MFMA16(A1, Bw01, MFMA16(A0, Bw00, z4));
            const floatx4 D1 = MFMA16(A1, Bw11, MFMA16(A0, Bw10, z4));
            #pragma unroll
            for (int r = 0; r < 4; ++r) {
                acc0 += leakyf(D0[r] + bs2c0);
                acc1 += leakyf(D1[r] + bs2c1);
            }
        }
        acc0 += __shfl_xor(acc0, 16, 64); acc0 += __shfl_xor(acc0, 32, 64);
        acc1 += __shfl_xor(acc1, 16, 64); acc1 += __shfl_xor(acc1, 32, 64);
        const int n = index_div[g * NGRP + jrow];
        if (quad == 0) {
            const float pv = (acc0 - sm.s.szero[cc]) * (1.0f / 31.0f);
            full_enc[n * HH + 32 + cc] = pv;
            sm.s.fe[jrow][32 + cc] = pv;
        } else if (quad == 1) {
            const float pv = (acc1 - sm.s.szero[16 + cc]) * (1.0f / 31.0f);
            full_enc[n * HH + 48 + cc] = pv;
            sm.s.fe[jrow][48 + cc] = pv;
        }
    }
    __syncthreads();

    // ---- head: x_logit = leaky(fe @ Wo1 + bo1) @ Wo2 + bo2 ----
    {
        const int veh = tid >> 4;          // 0..31
        const int p   = tid & 15;          // hidden dim
        float a = bo1[p];
        #pragma unroll
        for (int k = 0; k < HH; ++k)
            a = fmaf(sm.s.fe[veh][k], sm.s.swo1[k * 16 + p], a);
        a = leakyf(a);
        float l0 = a * Wo2[p * 3 + 0];
        float l1 = a * Wo2[p * 3 + 1];
        float l2 = a * Wo2[p * 3 + 2];
        #pragma unroll
        for (int off = 1; off < 16; off <<= 1) {
            l0 += __shfl_xor(l0, off, 64);
            l1 += __shfl_xor(l1, off, 64);
            l2 += __shfl_xor(l2, off, 64);
        }
        if (p == 0) {
            const int n = index_div[g * NGRP + veh];
            out[n * 3 + 0] = l0 + bo2[0];
            out[n * 3 + 1] = l1 + bo2[1];
            out[n * 3 + 2] = l2 + bo2[2];
        }
    }
}

// ---------------------------------------------------------------------------
extern "C" void kernel_launch(void* const* d_in, const int* in_sizes, int n_in,
                              void* d_out, int out_size, void* d_ws, size_t ws_size,
                              hipStream_t stream) {
    const float* scene     = (const float*)d_in[0];
    const int*   index_div = (const int*)d_in[4];
    const float* W_emb = (const float*)d_in[5];
    const float* b_emb = (const float*)d_in[6];
    const float* Wih_f = (const float*)d_in[7];
    const float* Whh_f = (const float*)d_in[8];
    const float* bih_f = (const float*)d_in[9];
    const float* bhh_f = (const float*)d_in[10];
    const float* Wih_b = (const float*)d_in[11];
    const float* Whh_b = (const float*)d_in[12];
    const float* bih_b = (const float*)d_in[13];
    const float* bhh_b = (const float*)d_in[14];
    const float* Wm  = (const float*)d_in[15];
    const float* bm  = (const float*)d_in[16];
    const float* Ws1 = (const float*)d_in[17];
    const float* bs1 = (const float*)d_in[18];
    const float* Ws2 = (const float*)d_in[19];
    const float* bs2 = (const float*)d_in[20];
    const float* Wo1 = (const float*)d_in[21];
    const float* bo1 = (const float*)d_in[22];
    const float* Wo2 = (const float*)d_in[23];
    const float* bo2 = (const float*)d_in[24];

    const int N = in_sizes[0] / (2 * TT);   // 32768
    const int G = in_sizes[4] / NGRP;       // 1024

    float* out      = (float*)d_out;
    float* full_enc = out + (size_t)N * CC;

    fused_kernel<<<dim3(G), dim3(512), 0, stream>>>(
        scene, index_div, W_emb, b_emb, Wih_f, Whh_f, bih_f, bhh_f,
        Wih_b, Whh_b, bih_b, bhh_b, Wm, bm, Ws1, bs1, Ws2, bs2,
        Wo1, bo1, Wo2, bo2, full_enc, out);
}